// Round 1
// baseline (8370.454 us; speedup 1.0000x reference)
//
#include <hip/hip_runtime.h>
#include <hip/hip_fp16.h>

#define LSEQ 4096
#define HD 256
#define GD 1024
#define NTAG 20
#define TAG_START 1
#define TAG_STOP 0
#define NEGV -10000.0f

typedef unsigned int u32;
typedef __attribute__((ext_vector_type(2))) _Float16 half2v;

#define USE_FDOT2 1
#if defined(__has_builtin)
#if !__has_builtin(__builtin_amdgcn_fdot2)
#undef USE_FDOT2
#define USE_FDOT2 0
#endif
#endif

__device__ __forceinline__ float dot2f(u32 w, u32 h, float acc) {
#if USE_FDOT2
  return __builtin_amdgcn_fdot2(__builtin_bit_cast(half2v, w),
                                __builtin_bit_cast(half2v, h), acc, false);
#else
  half2v a = __builtin_bit_cast(half2v, w);
  half2v b = __builtin_bit_cast(half2v, h);
  return acc + (float)a[0] * (float)b[0] + (float)a[1] * (float)b[1];
#endif
}

__device__ __forceinline__ u32 packh2(float a, float b) {
  half2v v;
  v[0] = (_Float16)a;
  v[1] = (_Float16)b;
  return __builtin_bit_cast(u32, v);
}

__device__ __forceinline__ unsigned short f16b(float a) {
  _Float16 h = (_Float16)a;
  return __builtin_bit_cast(unsigned short, h);
}

__device__ __forceinline__ float fsigm(float x) {
  return 1.0f / (1.0f + __expf(-x));
}
__device__ __forceinline__ float ftanh(float x) {
  float t = __expf(-2.0f * fabsf(x));
  float r = (1.0f - t) / (1.0f + t);
  return x < 0.0f ? -r : r;
}

// ---------------- K0: embedding gather ----------------
__global__ void gather_emb(const int* __restrict__ sent,
                           const float* __restrict__ etab,
                           float* __restrict__ emb) {
  const int t = blockIdx.x;
  const int l = threadIdx.x;
  const long long row = sent[t];
  *(float4*)&emb[t * HD + l * 4] = *(const float4*)&etab[row * HD + l * 4];
}

// ---------------- K1: xp = emb @ W_ih^T + (b_ih + b_hh), both dirs ----------------
__global__ __launch_bounds__(256) void xp_gemm(
    const float* __restrict__ emb, const float* __restrict__ Wf,
    const float* __restrict__ Wb, const float* __restrict__ bihf,
    const float* __restrict__ bhhf, const float* __restrict__ bihb,
    const float* __restrict__ bhhb, float* __restrict__ xpf,
    float* __restrict__ xpb) {
  const int dir = blockIdx.z;
  const float* __restrict__ W = dir ? Wb : Wf;
  const float* __restrict__ b1 = dir ? bihb : bihf;
  const float* __restrict__ b2 = dir ? bhhb : bhhf;
  float* __restrict__ out = dir ? xpb : xpf;
  __shared__ float As[32][64];
  __shared__ float Bs[32][64];
  const int bm = blockIdx.y * 64;
  const int bn = blockIdx.x * 64;
  const int tid = threadIdx.x;
  const int tx = tid & 15, ty = tid >> 4;
  const int lm = tid & 63, lk = tid >> 6;  // loader: row lm, k-quad lk
  float acc[4][4];
#pragma unroll
  for (int i = 0; i < 4; ++i)
#pragma unroll
    for (int j = 0; j < 4; ++j) acc[i][j] = 0.0f;

  for (int k0 = 0; k0 < HD; k0 += 32) {
    float4 a0 = *(const float4*)&emb[(bm + lm) * HD + k0 + lk * 4];
    float4 a1 = *(const float4*)&emb[(bm + lm) * HD + k0 + 16 + lk * 4];
    float4 c0 = *(const float4*)&W[(bn + lm) * HD + k0 + lk * 4];
    float4 c1 = *(const float4*)&W[(bn + lm) * HD + k0 + 16 + lk * 4];
    __syncthreads();
    As[lk * 4 + 0][lm] = a0.x;
    As[lk * 4 + 1][lm] = a0.y;
    As[lk * 4 + 2][lm] = a0.z;
    As[lk * 4 + 3][lm] = a0.w;
    As[16 + lk * 4 + 0][lm] = a1.x;
    As[16 + lk * 4 + 1][lm] = a1.y;
    As[16 + lk * 4 + 2][lm] = a1.z;
    As[16 + lk * 4 + 3][lm] = a1.w;
    Bs[lk * 4 + 0][lm] = c0.x;
    Bs[lk * 4 + 1][lm] = c0.y;
    Bs[lk * 4 + 2][lm] = c0.z;
    Bs[lk * 4 + 3][lm] = c0.w;
    Bs[16 + lk * 4 + 0][lm] = c1.x;
    Bs[16 + lk * 4 + 1][lm] = c1.y;
    Bs[16 + lk * 4 + 2][lm] = c1.z;
    Bs[16 + lk * 4 + 3][lm] = c1.w;
    __syncthreads();
#pragma unroll
    for (int k = 0; k < 32; ++k) {
      float4 av = *(const float4*)&As[k][ty * 4];
      float4 bv = *(const float4*)&Bs[k][tx * 4];
      float am[4] = {av.x, av.y, av.z, av.w};
      float bn_[4] = {bv.x, bv.y, bv.z, bv.w};
#pragma unroll
      for (int i = 0; i < 4; ++i)
#pragma unroll
        for (int j = 0; j < 4; ++j) acc[i][j] += am[i] * bn_[j];
    }
  }
#pragma unroll
  for (int i = 0; i < 4; ++i) {
    const int m = bm + ty * 4 + i;
#pragma unroll
    for (int j = 0; j < 4; ++j) {
      const int n = bn + tx * 4 + j;
      out[m * GD + n] = acc[i][j] + b1[n] + b2[n];
    }
  }
}

// ---------------- K2: sequential BiLSTM scan (grid = 2, one WG per direction) ----
// 512 threads, each owns output rows r0=2*tid, r1=2*tid+1 of z (4*H = 1024 rows).
// W_hh stored f16: k=0..191 in VGPRs (192 regs/thread), k=192..255 in LDS (128 KB).
// h broadcast as packed f16 in LDS; f32 accumulation via v_dot2_f32_f16.
__global__ __launch_bounds__(512, 2) void lstm_scan(
    const float* __restrict__ Whhf, const float* __restrict__ Whhb,
    const float* __restrict__ xpf, const float* __restrict__ xpb,
    const float* __restrict__ h0, const float* __restrict__ c0,
    float* __restrict__ hf, float* __restrict__ hb) {
  const int dir = blockIdx.x;
  const float* __restrict__ Whh = dir ? Whhb : Whhf;
  const float* __restrict__ xp = dir ? xpb : xpf;
  float* __restrict__ hout = dir ? hb : hf;
  const int tid = threadIdx.x;
  const int r0 = tid * 2, r1 = tid * 2 + 1;

  __shared__ unsigned short wldsA[8 * 512 * 8];  // 64 KB, rows r0, k=192..255
  __shared__ unsigned short wldsB[8 * 512 * 8];  // 64 KB, rows r1
  __shared__ unsigned short hbuf[2][HD];         // packed f16 h, ping-pong
  __shared__ float zbuf[GD];

  u32 wr0[96], wr1[96];
#pragma unroll
  for (int c = 0; c < 24; ++c) {
    float4 f0 = *(const float4*)&Whh[r0 * HD + c * 8];
    float4 f1 = *(const float4*)&Whh[r0 * HD + c * 8 + 4];
    wr0[c * 4 + 0] = packh2(f0.x, f0.y);
    wr0[c * 4 + 1] = packh2(f0.z, f0.w);
    wr0[c * 4 + 2] = packh2(f1.x, f1.y);
    wr0[c * 4 + 3] = packh2(f1.z, f1.w);
    float4 g0 = *(const float4*)&Whh[r1 * HD + c * 8];
    float4 g1 = *(const float4*)&Whh[r1 * HD + c * 8 + 4];
    wr1[c * 4 + 0] = packh2(g0.x, g0.y);
    wr1[c * 4 + 1] = packh2(g0.z, g0.w);
    wr1[c * 4 + 2] = packh2(g1.x, g1.y);
    wr1[c * 4 + 3] = packh2(g1.z, g1.w);
  }
#pragma unroll
  for (int c2 = 0; c2 < 8; ++c2) {
    float4 f0 = *(const float4*)&Whh[r0 * HD + 192 + c2 * 8];
    float4 f1 = *(const float4*)&Whh[r0 * HD + 192 + c2 * 8 + 4];
    uint4 p;
    p.x = packh2(f0.x, f0.y);
    p.y = packh2(f0.z, f0.w);
    p.z = packh2(f1.x, f1.y);
    p.w = packh2(f1.z, f1.w);
    *(uint4*)&wldsA[(c2 * 512 + tid) * 8] = p;
    float4 g0 = *(const float4*)&Whh[r1 * HD + 192 + c2 * 8];
    float4 g1 = *(const float4*)&Whh[r1 * HD + 192 + c2 * 8 + 4];
    uint4 q;
    q.x = packh2(g0.x, g0.y);
    q.y = packh2(g0.z, g0.w);
    q.z = packh2(g1.x, g1.y);
    q.w = packh2(g1.z, g1.w);
    *(uint4*)&wldsB[(c2 * 512 + tid) * 8] = q;
  }
  float cst = 0.0f;
  if (tid < HD) {
    cst = c0[dir * HD + tid];
    hbuf[0][tid] = f16b(h0[dir * HD + tid]);
  }
  __syncthreads();

  for (int s = 0; s < LSEQ; ++s) {
    const int t = dir ? (LSEQ - 1 - s) : s;
    const int par = s & 1;
    const float2 xv = *(const float2*)&xp[t * GD + r0];
    float a0 = 0.f, b0 = 0.f, a1 = 0.f, b1 = 0.f;
    const uint4* h4 = (const uint4*)&hbuf[par][0];
#pragma unroll
    for (int c = 0; c < 24; ++c) {
      uint4 hc = h4[c];
      a0 = dot2f(wr0[c * 4 + 0], hc.x, a0);
      b0 = dot2f(wr0[c * 4 + 1], hc.y, b0);
      a0 = dot2f(wr0[c * 4 + 2], hc.z, a0);
      b0 = dot2f(wr0[c * 4 + 3], hc.w, b0);
      a1 = dot2f(wr1[c * 4 + 0], hc.x, a1);
      b1 = dot2f(wr1[c * 4 + 1], hc.y, b1);
      a1 = dot2f(wr1[c * 4 + 2], hc.z, a1);
      b1 = dot2f(wr1[c * 4 + 3], hc.w, b1);
    }
#pragma unroll
    for (int c2 = 0; c2 < 8; ++c2) {
      uint4 hc = h4[24 + c2];
      uint4 w0 = *(const uint4*)&wldsA[(c2 * 512 + tid) * 8];
      uint4 w1 = *(const uint4*)&wldsB[(c2 * 512 + tid) * 8];
      a0 = dot2f(w0.x, hc.x, a0);
      b0 = dot2f(w0.y, hc.y, b0);
      a0 = dot2f(w0.z, hc.z, a0);
      b0 = dot2f(w0.w, hc.w, b0);
      a1 = dot2f(w1.x, hc.x, a1);
      b1 = dot2f(w1.y, hc.y, b1);
      a1 = dot2f(w1.z, hc.z, a1);
      b1 = dot2f(w1.w, hc.w, b1);
    }
    float2 zz;
    zz.x = xv.x + a0 + b0;
    zz.y = xv.y + a1 + b1;
    *(float2*)&zbuf[r0] = zz;
    __syncthreads();
    if (tid < HD) {
      const float zi = zbuf[tid];
      const float zf = zbuf[HD + tid];
      const float zg = zbuf[2 * HD + tid];
      const float zo = zbuf[3 * HD + tid];
      const float ig = fsigm(zi), fg = fsigm(zf), gg = ftanh(zg),
                  og = fsigm(zo);
      const float cv = fg * cst + ig * gg;
      cst = cv;
      const float hv = og * ftanh(cv);
      hout[t * HD + tid] = hv;
      hbuf[par ^ 1][tid] = f16b(hv);
    }
    __syncthreads();
  }
}

// ---------------- K3: feats = [hf|hb] @ W_out^T + b_out ----------------
__global__ __launch_bounds__(256) void feats_kernel(
    const float* __restrict__ hf, const float* __restrict__ hb,
    const float* __restrict__ Wout, const float* __restrict__ bout,
    float* __restrict__ feats) {
  __shared__ float Ws[NTAG][520];  // padded: avoid 20-way bank conflict
  __shared__ float bs[NTAG];
  const int tid = threadIdx.x;
  for (int i = tid; i < NTAG * 512; i += 256) Ws[i / 512][i % 512] = Wout[i];
  if (tid < NTAG) bs[tid] = bout[tid];
  __syncthreads();
  const int t0 = blockIdx.x * 32;
  for (int idx = tid; idx < 32 * NTAG; idx += 256) {
    const int t = t0 + idx / NTAG;
    const int tag = idx % NTAG;
    const float* __restrict__ hfr = &hf[t * HD];
    const float* __restrict__ hbr = &hb[t * HD];
    float s = bs[tag];
#pragma unroll 8
    for (int k = 0; k < HD; ++k) {
      s += hfr[k] * Ws[tag][k];
      s += hbr[k] * Ws[tag][HD + k];
    }
    feats[t * NTAG + tag] = s;
  }
}

// ---------------- K4: Viterbi decode (single wave) + chunked backtrack --------
__global__ __launch_bounds__(64) void viterbi_kernel(
    const float* __restrict__ feats, const float* __restrict__ trans,
    float* __restrict__ out) {
  __shared__ unsigned char bp[LSEQ * NTAG];  // 80 KB backpointers
  __shared__ float fvb[32];
  __shared__ float termb[32];
  __shared__ unsigned char fmap[64][NTAG];
  __shared__ unsigned char bnd[64];
  const int lane = threadIdx.x;
  const int nt = lane < NTAG ? lane : 0;
  float tr[NTAG];
#pragma unroll
  for (int p = 0; p < NTAG; ++p) tr[p] = trans[nt * NTAG + p];
  if (lane < NTAG) fvb[lane] = (lane == TAG_START) ? 0.0f : NEGV;
  __syncthreads();

  float fcur[8], fnxt[8];
#pragma unroll
  for (int i = 0; i < 8; ++i) fcur[i] = feats[i * NTAG + nt];
  for (int t0 = 0; t0 < LSEQ; t0 += 8) {
#pragma unroll
    for (int i = 0; i < 8; ++i) {
      const int tt = t0 + 8 + i;
      fnxt[i] = (tt < LSEQ) ? feats[tt * NTAG + nt] : 0.0f;
    }
#pragma unroll
    for (int i = 0; i < 8; ++i) {
      const int t = t0 + i;
      float best = fvb[0] + tr[0];
      int bi = 0;
#pragma unroll
      for (int p = 1; p < NTAG; ++p) {
        const float v = fvb[p] + tr[p];
        if (v > best) {
          best = v;
          bi = p;
        }
      }
      const float nv = best + fcur[i];
      if (lane < NTAG) {
        fvb[lane] = nv;
        bp[t * NTAG + lane] = (unsigned char)bi;
      }
    }
#pragma unroll
    for (int i = 0; i < 8; ++i) fcur[i] = fnxt[i];
  }

  if (lane < NTAG) termb[lane] = fvb[lane] + trans[TAG_STOP * NTAG + lane];
  __syncthreads();
  if (lane == 0) {
    float best = termb[0];
    int bi = 0;
#pragma unroll
    for (int p = 1; p < NTAG; ++p) {
      const float v = termb[p];
      if (v > best) {
        best = v;
        bi = p;
      }
    }
    out[0] = best;
    bnd[63] = (unsigned char)bi;
  }
  __syncthreads();

  // compose per-chunk backpointer maps (64 steps each) in parallel
  {
    const int c = lane;
    int m[NTAG];
#pragma unroll
    for (int e = 0; e < NTAG; ++e) m[e] = e;
    for (int s = 63; s >= 0; --s) {
      const int base = (c * 64 + s) * NTAG;
#pragma unroll
      for (int e = 0; e < NTAG; ++e) m[e] = bp[base + m[e]];
    }
#pragma unroll
    for (int e = 0; e < NTAG; ++e) fmap[c][e] = (unsigned char)m[e];
  }
  __syncthreads();
  if (lane == 0) {
    for (int cc = 63; cc >= 1; --cc) bnd[cc - 1] = fmap[cc][bnd[cc]];
  }
  __syncthreads();
  // per-lane backtrack inside own chunk
  {
    const int c = lane;
    int cur = bnd[c];
    out[1 + c * 64 + 63] = (float)cur;
    for (int s2 = 63; s2 >= 1; --s2) {
      cur = bp[(c * 64 + s2) * NTAG + cur];
      out[1 + c * 64 + s2 - 1] = (float)cur;
    }
  }
}

extern "C" void kernel_launch(void* const* d_in, const int* in_sizes, int n_in,
                              void* d_out, int out_size, void* d_ws,
                              size_t ws_size, hipStream_t stream) {
  const int* sentence = (const int*)d_in[0];
  const float* etab = (const float*)d_in[1];
  const float* Wihf = (const float*)d_in[2];
  const float* Whhf = (const float*)d_in[3];
  const float* bihf = (const float*)d_in[4];
  const float* bhhf = (const float*)d_in[5];
  const float* Wihb = (const float*)d_in[6];
  const float* Whhb = (const float*)d_in[7];
  const float* bihb = (const float*)d_in[8];
  const float* bhhb = (const float*)d_in[9];
  const float* Wout = (const float*)d_in[10];
  const float* bout = (const float*)d_in[11];
  const float* trans = (const float*)d_in[12];
  const float* h0 = (const float*)d_in[13];
  const float* c0 = (const float*)d_in[14];

  float* ws = (float*)d_ws;
  float* xpf = ws;
  float* xpb = xpf + (size_t)LSEQ * GD;
  float* hfp = xpb + (size_t)LSEQ * GD;
  float* hbp = hfp + (size_t)LSEQ * HD;
  float* emb = hbp + (size_t)LSEQ * HD;
  float* feats = emb + (size_t)LSEQ * HD;
  float* outp = (float*)d_out;

  gather_emb<<<LSEQ, 64, 0, stream>>>(sentence, etab, emb);
  xp_gemm<<<dim3(GD / 64, LSEQ / 64, 2), 256, 0, stream>>>(
      emb, Wihf, Wihb, bihf, bhhf, bihb, bhhb, xpf, xpb);
  lstm_scan<<<2, 512, 0, stream>>>(Whhf, Whhb, xpf, xpb, h0, c0, hfp, hbp);
  feats_kernel<<<LSEQ / 32, 256, 0, stream>>>(hfp, hbp, Wout, bout, feats);
  viterbi_kernel<<<1, 64, 0, stream>>>(feats, trans, outp);
}

// Round 2
// 7611.189 us; speedup vs baseline: 1.0998x; 1.0998x over previous
//
#include <hip/hip_runtime.h>
#include <hip/hip_fp16.h>

#define LSEQ 4096
#define HD 256
#define GD 1024
#define NTAG 20
#define TAG_START 1
#define TAG_STOP 0
#define NEGV -10000.0f

typedef unsigned int u32;
typedef __attribute__((ext_vector_type(2))) _Float16 half2v;

#define USE_FDOT2 1
#if defined(__has_builtin)
#if !__has_builtin(__builtin_amdgcn_fdot2)
#undef USE_FDOT2
#define USE_FDOT2 0
#endif
#endif

__device__ __forceinline__ float dot2f(u32 w, u32 h, float acc) {
#if USE_FDOT2
  return __builtin_amdgcn_fdot2(__builtin_bit_cast(half2v, w),
                                __builtin_bit_cast(half2v, h), acc, false);
#else
  half2v a = __builtin_bit_cast(half2v, w);
  half2v b = __builtin_bit_cast(half2v, h);
  return acc + (float)a[0] * (float)b[0] + (float)a[1] * (float)b[1];
#endif
}

__device__ __forceinline__ u32 packh2(float a, float b) {
  half2v v;
  v[0] = (_Float16)a;
  v[1] = (_Float16)b;
  return __builtin_bit_cast(u32, v);
}

__device__ __forceinline__ unsigned short f16b(float a) {
  _Float16 h = (_Float16)a;
  return __builtin_bit_cast(unsigned short, h);
}

// quad_perm DPP cross-lane adds (VALU-only, no LDS pipe)
__device__ __forceinline__ float dpp_add_xor1(float x) {
  int y = __builtin_amdgcn_mov_dpp(__builtin_bit_cast(int, x), 0xB1, 0xF, 0xF,
                                   true);  // quad_perm(1,0,3,2)
  return x + __builtin_bit_cast(float, y);
}
__device__ __forceinline__ float dpp_add_xor2(float x) {
  int y = __builtin_amdgcn_mov_dpp(__builtin_bit_cast(int, x), 0x4E, 0xF, 0xF,
                                   true);  // quad_perm(2,3,0,1)
  return x + __builtin_bit_cast(float, y);
}

__device__ __forceinline__ float fsigm(float x) {
  return 1.0f / (1.0f + __expf(-x));
}
__device__ __forceinline__ float ftanh(float x) {
  float t = __expf(-2.0f * fabsf(x));
  float r = (1.0f - t) / (1.0f + t);
  return x < 0.0f ? -r : r;
}

// ---------------- K0: embedding gather ----------------
__global__ void gather_emb(const int* __restrict__ sent,
                           const float* __restrict__ etab,
                           float* __restrict__ emb) {
  const int t = blockIdx.x;
  const int l = threadIdx.x;
  const long long row = sent[t];
  *(float4*)&emb[t * HD + l * 4] = *(const float4*)&etab[row * HD + l * 4];
}

// ---------------- K1: xp = emb @ W_ih^T + (b_ih + b_hh), both dirs ----------------
__global__ __launch_bounds__(256) void xp_gemm(
    const float* __restrict__ emb, const float* __restrict__ Wf,
    const float* __restrict__ Wb, const float* __restrict__ bihf,
    const float* __restrict__ bhhf, const float* __restrict__ bihb,
    const float* __restrict__ bhhb, float* __restrict__ xpf,
    float* __restrict__ xpb) {
  const int dir = blockIdx.z;
  const float* __restrict__ W = dir ? Wb : Wf;
  const float* __restrict__ b1 = dir ? bihb : bihf;
  const float* __restrict__ b2 = dir ? bhhb : bhhf;
  float* __restrict__ out = dir ? xpb : xpf;
  __shared__ float As[32][64];
  __shared__ float Bs[32][64];
  const int bm = blockIdx.y * 64;
  const int bn = blockIdx.x * 64;
  const int tid = threadIdx.x;
  const int tx = tid & 15, ty = tid >> 4;
  const int lm = tid & 63, lk = tid >> 6;  // loader: row lm, k-quad lk
  float acc[4][4];
#pragma unroll
  for (int i = 0; i < 4; ++i)
#pragma unroll
    for (int j = 0; j < 4; ++j) acc[i][j] = 0.0f;

  for (int k0 = 0; k0 < HD; k0 += 32) {
    float4 a0 = *(const float4*)&emb[(bm + lm) * HD + k0 + lk * 4];
    float4 a1 = *(const float4*)&emb[(bm + lm) * HD + k0 + 16 + lk * 4];
    float4 c0 = *(const float4*)&W[(bn + lm) * HD + k0 + lk * 4];
    float4 c1 = *(const float4*)&W[(bn + lm) * HD + k0 + 16 + lk * 4];
    __syncthreads();
    As[lk * 4 + 0][lm] = a0.x;
    As[lk * 4 + 1][lm] = a0.y;
    As[lk * 4 + 2][lm] = a0.z;
    As[lk * 4 + 3][lm] = a0.w;
    As[16 + lk * 4 + 0][lm] = a1.x;
    As[16 + lk * 4 + 1][lm] = a1.y;
    As[16 + lk * 4 + 2][lm] = a1.z;
    As[16 + lk * 4 + 3][lm] = a1.w;
    Bs[lk * 4 + 0][lm] = c0.x;
    Bs[lk * 4 + 1][lm] = c0.y;
    Bs[lk * 4 + 2][lm] = c0.z;
    Bs[lk * 4 + 3][lm] = c0.w;
    Bs[16 + lk * 4 + 0][lm] = c1.x;
    Bs[16 + lk * 4 + 1][lm] = c1.y;
    Bs[16 + lk * 4 + 2][lm] = c1.z;
    Bs[16 + lk * 4 + 3][lm] = c1.w;
    __syncthreads();
#pragma unroll
    for (int k = 0; k < 32; ++k) {
      float4 av = *(const float4*)&As[k][ty * 4];
      float4 bv = *(const float4*)&Bs[k][tx * 4];
      float am[4] = {av.x, av.y, av.z, av.w};
      float bn_[4] = {bv.x, bv.y, bv.z, bv.w};
#pragma unroll
      for (int i = 0; i < 4; ++i)
#pragma unroll
        for (int j = 0; j < 4; ++j) acc[i][j] += am[i] * bn_[j];
    }
  }
#pragma unroll
  for (int i = 0; i < 4; ++i) {
    const int m = bm + ty * 4 + i;
#pragma unroll
    for (int j = 0; j < 4; ++j) {
      const int n = bn + tx * 4 + j;
      out[m * GD + n] = acc[i][j] + b1[n] + b2[n];
    }
  }
}

// ---------------- K2: sequential BiLSTM scan (grid = 2, one WG per direction) ----
// k-split design: thread tid -> row-group g=tid>>2 (8 rows), k-chunk q=tid&3
// (64 k each). Per step each thread reads only 128 B of h (8 b128) instead of
// 512 B. Rows j=0..5 weights resident in regs (192 u32), rows 6,7 streamed
// from LDS in conflict-free [chunk][tid][16B] layout. 4-way k-partials reduced
// via DPP quad_perm adds (VALU-only). Gates add xp (prefetched) post-barrier.
__global__ __launch_bounds__(512, 2) void lstm_scan(
    const float* __restrict__ Whhf, const float* __restrict__ Whhb,
    const float* __restrict__ xpf, const float* __restrict__ xpb,
    const float* __restrict__ h0, const float* __restrict__ c0,
    float* __restrict__ hf, float* __restrict__ hb) {
  const int dir = blockIdx.x;
  const float* __restrict__ Whh = dir ? Whhb : Whhf;
  const float* __restrict__ xp = dir ? xpb : xpf;
  float* __restrict__ hout = dir ? hb : hf;
  const int tid = threadIdx.x;
  const int g = tid >> 2;      // row group: rows g*8 .. g*8+7
  const int q = tid & 3;       // k chunk:   k in [64q, 64q+64)
  const int kb = q * 64;       // k base (f16 elems)

  __shared__ uint4 wlds[16][512];            // 128 KB streamed weights
  __shared__ unsigned short hbuf[2][4 * 80]; // padded f16 h chunks, ping-pong
  __shared__ float zbuf[GD];                 // 4 KB

  // resident weights: rows j=0..5, 64 k each -> 192 u32
  u32 wres[192];
#pragma unroll
  for (int j = 0; j < 6; ++j) {
    const int row = g * 8 + j;
#pragma unroll
    for (int v4 = 0; v4 < 16; ++v4) {
      float4 f = *(const float4*)&Whh[row * HD + kb + v4 * 4];
      wres[j * 32 + v4 * 2 + 0] = packh2(f.x, f.y);
      wres[j * 32 + v4 * 2 + 1] = packh2(f.z, f.w);
    }
  }
  // streamed weights: rows 6,7 -> wlds[c][tid], c = (row-6)*8 + sub
#pragma unroll
  for (int c = 0; c < 16; ++c) {
    const int row = g * 8 + 6 + (c >> 3);
    const int k2 = kb + (c & 7) * 8;
    float4 f0 = *(const float4*)&Whh[row * HD + k2];
    float4 f1 = *(const float4*)&Whh[row * HD + k2 + 4];
    uint4 p;
    p.x = packh2(f0.x, f0.y);
    p.y = packh2(f0.z, f0.w);
    p.z = packh2(f1.x, f1.y);
    p.w = packh2(f1.z, f1.w);
    wlds[c][tid] = p;
  }
  float cst = 0.0f;
  if (tid < HD) {
    cst = c0[dir * HD + tid];
    hbuf[0][(tid >> 6) * 80 + (tid & 63)] = f16b(h0[dir * HD + tid]);
  }
  __syncthreads();

  for (int s = 0; s < LSEQ; ++s) {
    const int t = dir ? (LSEQ - 1 - s) : s;
    const int par = s & 1;
    // prefetch xp for this step's gate phase (consumed after the barrier)
    float xg0 = 0.f, xg1 = 0.f, xg2 = 0.f, xg3 = 0.f;
    if (tid < HD) {
      xg0 = xp[t * GD + tid];
      xg1 = xp[t * GD + HD + tid];
      xg2 = xp[t * GD + 2 * HD + tid];
      xg3 = xp[t * GD + 3 * HD + tid];
    }
    const uint4* hsrc = (const uint4*)&hbuf[par][q * 80];
    float a0 = 0.f, a1 = 0.f, a2 = 0.f, a3 = 0.f;
    float a4 = 0.f, a5 = 0.f, a6 = 0.f, a7 = 0.f;
#pragma unroll
    for (int half = 0; half < 2; ++half) {
      const uint4 hva = hsrc[half * 4 + 0];
      const uint4 hvb = hsrc[half * 4 + 1];
      const uint4 hvc = hsrc[half * 4 + 2];
      const uint4 hvd = hsrc[half * 4 + 3];
      const u32 hh[16] = {hva.x, hva.y, hva.z, hva.w, hvb.x, hvb.y,
                          hvb.z, hvb.w, hvc.x, hvc.y, hvc.z, hvc.w,
                          hvd.x, hvd.y, hvd.z, hvd.w};
      // resident rows 0..5
#pragma unroll
      for (int m = 0; m < 16; ++m) {
        a0 = dot2f(wres[0 * 32 + half * 16 + m], hh[m], a0);
        a1 = dot2f(wres[1 * 32 + half * 16 + m], hh[m], a1);
        a2 = dot2f(wres[2 * 32 + half * 16 + m], hh[m], a2);
        a3 = dot2f(wres[3 * 32 + half * 16 + m], hh[m], a3);
        a4 = dot2f(wres[4 * 32 + half * 16 + m], hh[m], a4);
        a5 = dot2f(wres[5 * 32 + half * 16 + m], hh[m], a5);
      }
      // streamed rows 6,7
#pragma unroll
      for (int cc = 0; cc < 4; ++cc) {
        const uint4 wa = wlds[half * 4 + cc][tid];
        a6 = dot2f(wa.x, hh[cc * 4 + 0], a6);
        a6 = dot2f(wa.y, hh[cc * 4 + 1], a6);
        a6 = dot2f(wa.z, hh[cc * 4 + 2], a6);
        a6 = dot2f(wa.w, hh[cc * 4 + 3], a6);
        const uint4 wb = wlds[8 + half * 4 + cc][tid];
        a7 = dot2f(wb.x, hh[cc * 4 + 0], a7);
        a7 = dot2f(wb.y, hh[cc * 4 + 1], a7);
        a7 = dot2f(wb.z, hh[cc * 4 + 2], a7);
        a7 = dot2f(wb.w, hh[cc * 4 + 3], a7);
      }
    }
    // 4-way k-reduction within each lane quad (VALU-only DPP)
    a0 = dpp_add_xor2(dpp_add_xor1(a0));
    a1 = dpp_add_xor2(dpp_add_xor1(a1));
    a2 = dpp_add_xor2(dpp_add_xor1(a2));
    a3 = dpp_add_xor2(dpp_add_xor1(a3));
    a4 = dpp_add_xor2(dpp_add_xor1(a4));
    a5 = dpp_add_xor2(dpp_add_xor1(a5));
    a6 = dpp_add_xor2(dpp_add_xor1(a6));
    a7 = dpp_add_xor2(dpp_add_xor1(a7));
    // lane q of each quad writes rows g*8+q and g*8+q+4 (compile-time select)
    const float zA = (q == 0) ? a0 : (q == 1) ? a1 : (q == 2) ? a2 : a3;
    const float zB = (q == 0) ? a4 : (q == 1) ? a5 : (q == 2) ? a6 : a7;
    zbuf[g * 8 + q] = zA;
    zbuf[g * 8 + q + 4] = zB;
    __syncthreads();
    if (tid < HD) {
      const float zi = zbuf[tid] + xg0;
      const float zf = zbuf[HD + tid] + xg1;
      const float zg = zbuf[2 * HD + tid] + xg2;
      const float zo = zbuf[3 * HD + tid] + xg3;
      const float ig = fsigm(zi), fg = fsigm(zf), gg = ftanh(zg),
                  og = fsigm(zo);
      const float cv = fg * cst + ig * gg;
      cst = cv;
      const float hv = og * ftanh(cv);
      hout[t * HD + tid] = hv;
      hbuf[par ^ 1][(tid >> 6) * 80 + (tid & 63)] = f16b(hv);
    }
    __syncthreads();
  }
}

// ---------------- K3: feats = [hf|hb] @ W_out^T + b_out ----------------
__global__ __launch_bounds__(256) void feats_kernel(
    const float* __restrict__ hf, const float* __restrict__ hb,
    const float* __restrict__ Wout, const float* __restrict__ bout,
    float* __restrict__ feats) {
  __shared__ float Ws[NTAG][520];  // padded: avoid 20-way bank conflict
  __shared__ float bs[NTAG];
  const int tid = threadIdx.x;
  for (int i = tid; i < NTAG * 512; i += 256) Ws[i / 512][i % 512] = Wout[i];
  if (tid < NTAG) bs[tid] = bout[tid];
  __syncthreads();
  const int t0 = blockIdx.x * 32;
  for (int idx = tid; idx < 32 * NTAG; idx += 256) {
    const int t = t0 + idx / NTAG;
    const int tag = idx % NTAG;
    const float* __restrict__ hfr = &hf[t * HD];
    const float* __restrict__ hbr = &hb[t * HD];
    float s = bs[tag];
#pragma unroll 8
    for (int k = 0; k < HD; ++k) {
      s += hfr[k] * Ws[tag][k];
      s += hbr[k] * Ws[tag][HD + k];
    }
    feats[t * NTAG + tag] = s;
  }
}

// ---------------- K4: Viterbi decode (single wave) + chunked backtrack --------
__global__ __launch_bounds__(64) void viterbi_kernel(
    const float* __restrict__ feats, const float* __restrict__ trans,
    float* __restrict__ out) {
  __shared__ unsigned char bp[LSEQ * NTAG];  // 80 KB backpointers
  __shared__ float fvb[32];
  __shared__ float termb[32];
  __shared__ unsigned char fmap[64][NTAG];
  __shared__ unsigned char bnd[64];
  const int lane = threadIdx.x;
  const int nt = lane < NTAG ? lane : 0;
  float tr[NTAG];
#pragma unroll
  for (int p = 0; p < NTAG; ++p) tr[p] = trans[nt * NTAG + p];
  if (lane < NTAG) fvb[lane] = (lane == TAG_START) ? 0.0f : NEGV;
  __syncthreads();

  float fcur[8], fnxt[8];
#pragma unroll
  for (int i = 0; i < 8; ++i) fcur[i] = feats[i * NTAG + nt];
  for (int t0 = 0; t0 < LSEQ; t0 += 8) {
#pragma unroll
    for (int i = 0; i < 8; ++i) {
      const int tt = t0 + 8 + i;
      fnxt[i] = (tt < LSEQ) ? feats[tt * NTAG + nt] : 0.0f;
    }
#pragma unroll
    for (int i = 0; i < 8; ++i) {
      const int t = t0 + i;
      float best = fvb[0] + tr[0];
      int bi = 0;
#pragma unroll
      for (int p = 1; p < NTAG; ++p) {
        const float v = fvb[p] + tr[p];
        if (v > best) {
          best = v;
          bi = p;
        }
      }
      const float nv = best + fcur[i];
      if (lane < NTAG) {
        fvb[lane] = nv;
        bp[t * NTAG + lane] = (unsigned char)bi;
      }
    }
#pragma unroll
    for (int i = 0; i < 8; ++i) fcur[i] = fnxt[i];
  }

  if (lane < NTAG) termb[lane] = fvb[lane] + trans[TAG_STOP * NTAG + lane];
  __syncthreads();
  if (lane == 0) {
    float best = termb[0];
    int bi = 0;
#pragma unroll
    for (int p = 1; p < NTAG; ++p) {
      const float v = termb[p];
      if (v > best) {
        best = v;
        bi = p;
      }
    }
    out[0] = best;
    bnd[63] = (unsigned char)bi;
  }
  __syncthreads();

  // compose per-chunk backpointer maps (64 steps each) in parallel
  {
    const int c = lane;
    int m[NTAG];
#pragma unroll
    for (int e = 0; e < NTAG; ++e) m[e] = e;
    for (int s = 63; s >= 0; --s) {
      const int base = (c * 64 + s) * NTAG;
#pragma unroll
      for (int e = 0; e < NTAG; ++e) m[e] = bp[base + m[e]];
    }
#pragma unroll
    for (int e = 0; e < NTAG; ++e) fmap[c][e] = (unsigned char)m[e];
  }
  __syncthreads();
  if (lane == 0) {
    for (int cc = 63; cc >= 1; --cc) bnd[cc - 1] = fmap[cc][bnd[cc]];
  }
  __syncthreads();
  // per-lane backtrack inside own chunk
  {
    const int c = lane;
    int cur = bnd[c];
    out[1 + c * 64 + 63] = (float)cur;
    for (int s2 = 63; s2 >= 1; --s2) {
      cur = bp[(c * 64 + s2) * NTAG + cur];
      out[1 + c * 64 + s2 - 1] = (float)cur;
    }
  }
}

extern "C" void kernel_launch(void* const* d_in, const int* in_sizes, int n_in,
                              void* d_out, int out_size, void* d_ws,
                              size_t ws_size, hipStream_t stream) {
  const int* sentence = (const int*)d_in[0];
  const float* etab = (const float*)d_in[1];
  const float* Wihf = (const float*)d_in[2];
  const float* Whhf = (const float*)d_in[3];
  const float* bihf = (const float*)d_in[4];
  const float* bhhf = (const float*)d_in[5];
  const float* Wihb = (const float*)d_in[6];
  const float* Whhb = (const float*)d_in[7];
  const float* bihb = (const float*)d_in[8];
  const float* bhhb = (const float*)d_in[9];
  const float* Wout = (const float*)d_in[10];
  const float* bout = (const float*)d_in[11];
  const float* trans = (const float*)d_in[12];
  const float* h0 = (const float*)d_in[13];
  const float* c0 = (const float*)d_in[14];

  float* ws = (float*)d_ws;
  float* xpf = ws;
  float* xpb = xpf + (size_t)LSEQ * GD;
  float* hfp = xpb + (size_t)LSEQ * GD;
  float* hbp = hfp + (size_t)LSEQ * HD;
  float* emb = hbp + (size_t)LSEQ * HD;
  float* feats = emb + (size_t)LSEQ * HD;
  float* outp = (float*)d_out;

  gather_emb<<<LSEQ, 64, 0, stream>>>(sentence, etab, emb);
  xp_gemm<<<dim3(GD / 64, LSEQ / 64, 2), 256, 0, stream>>>(
      emb, Wihf, Wihb, bihf, bhhf, bihb, bhhb, xpf, xpb);
  lstm_scan<<<2, 512, 0, stream>>>(Whhf, Whhb, xpf, xpb, h0, c0, hfp, hbp);
  feats_kernel<<<LSEQ / 32, 256, 0, stream>>>(hfp, hbp, Wout, bout, feats);
  viterbi_kernel<<<1, 64, 0, stream>>>(feats, trans, outp);
}